// Round 1
// baseline (223.367 us; speedup 1.0000x reference)
//
#include <hip/hip_runtime.h>

// skipgram negative-sampling loss, MI355X.
// One wave (64 lanes) per batch row; float2/lane covers DIM=128.
// neg_score is summed over K before logsigmoid, so sum the K neg rows
// elementwise first and do a single dot -> only 2 wave reductions per row.

constexpr int DIM = 128;
constexpr int KNEG = 20;

__device__ __forceinline__ float log_sigmoid(float x) {
    // stable: min(x,0) - log1p(exp(-|x|))
    return fminf(x, 0.0f) - log1pf(__expf(-fabsf(x)));
}

__global__ __launch_bounds__(256) void skipgram_kernel(
    const float* __restrict__ u_emb, const float* __restrict__ v_emb,
    const int* __restrict__ u_pos, const int* __restrict__ v_pos,
    const int* __restrict__ v_neg, float* __restrict__ out,
    int B, float neg_inv_b)
{
    int wid  = (int)((blockIdx.x * blockDim.x + threadIdx.x) >> 6);  // wave id = row
    int lane = threadIdx.x & 63;
    if (wid >= B) return;

    const float2* urow = reinterpret_cast<const float2*>(u_emb + (size_t)u_pos[wid] * DIM);
    const float2* vrow = reinterpret_cast<const float2*>(v_emb + (size_t)v_pos[wid] * DIM);
    float2 uu = urow[lane];
    float2 vv = vrow[lane];
    float pos = uu.x * vv.x + uu.y * vv.y;

    const int* __restrict__ negs = v_neg + (size_t)wid * KNEG;
    float accx = 0.0f, accy = 0.0f;
    #pragma unroll
    for (int k = 0; k < KNEG; ++k) {
        const float2* nrow = reinterpret_cast<const float2*>(v_emb + (size_t)negs[k] * DIM);
        float2 nv = nrow[lane];
        accx += nv.x;
        accy += nv.y;
    }
    float neg = uu.x * accx + uu.y * accy;

    // 64-lane butterfly reduction of both dots
    #pragma unroll
    for (int off = 32; off; off >>= 1) {
        pos += __shfl_xor(pos, off);
        neg += __shfl_xor(neg, off);
    }

    if (lane == 0) {
        float loss = log_sigmoid(pos) + log_sigmoid(-neg);
        atomicAdd(out, loss * neg_inv_b);   // neg_inv_b = -1/B
    }
}

extern "C" void kernel_launch(void* const* d_in, const int* in_sizes, int n_in,
                              void* d_out, int out_size, void* d_ws, size_t ws_size,
                              hipStream_t stream) {
    const float* u_emb = (const float*)d_in[0];
    const float* v_emb = (const float*)d_in[1];
    const int*   u_pos = (const int*)d_in[2];
    const int*   v_pos = (const int*)d_in[3];
    const int*   v_neg = (const int*)d_in[4];
    float* out = (float*)d_out;

    const int B = in_sizes[2];            // 16384

    hipMemsetAsync(out, 0, sizeof(float), stream);

    const int waves_per_block = 4;        // 256 threads
    const int blocks = (B + waves_per_block - 1) / waves_per_block;
    skipgram_kernel<<<blocks, 256, 0, stream>>>(
        u_emb, v_emb, u_pos, v_pos, v_neg, out, B, -1.0f / (float)B);
}

// Round 2
// 40.661 us; speedup vs baseline: 5.4934x; 5.4934x over previous
//
#include <hip/hip_runtime.h>

// skipgram negative-sampling loss, MI355X.
// One wave (64 lanes) per batch row, grid-stride over rows; float2/lane covers DIM=128.
// neg_score is summed over K before logsigmoid -> sum the K neg rows elementwise,
// single dot, one butterfly per row. Per-block LDS reduce -> 1024 atomics total.

constexpr int DIM  = 128;
constexpr int KNEG = 20;
constexpr int WAVES_PER_BLOCK = 4;

__device__ __forceinline__ float log_sigmoid(float x) {
    // stable: min(x,0) - log1p(exp(-|x|))
    return fminf(x, 0.0f) - log1pf(__expf(-fabsf(x)));
}

__global__ __launch_bounds__(256) void skipgram_kernel(
    const float* __restrict__ u_emb, const float* __restrict__ v_emb,
    const int* __restrict__ u_pos, const int* __restrict__ v_pos,
    const int* __restrict__ v_neg, float* __restrict__ out,
    int B, float neg_inv_b)
{
    const int wslot = threadIdx.x >> 6;
    const int lane  = threadIdx.x & 63;
    const int gwid  = blockIdx.x * WAVES_PER_BLOCK + wslot;
    const int nwav  = gridDim.x * WAVES_PER_BLOCK;

    float lsum = 0.0f;

    for (int row = gwid; row < B; row += nwav) {
        // ---- issue ALL loads for this row up front (MLP) ----
        const int up = u_pos[row];
        const int vp = v_pos[row];
        int idx[KNEG];
        #pragma unroll
        for (int k = 0; k < KNEG; ++k) idx[k] = v_neg[row * KNEG + k];

        const float2 uu = reinterpret_cast<const float2*>(u_emb + (size_t)up * DIM)[lane];
        const float2 vv = reinterpret_cast<const float2*>(v_emb + (size_t)vp * DIM)[lane];

        float2 nv[KNEG];
        #pragma unroll
        for (int k = 0; k < KNEG; ++k)
            nv[k] = reinterpret_cast<const float2*>(v_emb + (size_t)idx[k] * DIM)[lane];

        // ---- compute ----
        float pos = fmaf(uu.x, vv.x, uu.y * vv.y);
        float accx = 0.0f, accy = 0.0f;
        #pragma unroll
        for (int k = 0; k < KNEG; ++k) { accx += nv[k].x; accy += nv[k].y; }
        float neg = fmaf(uu.x, accx, uu.y * accy);

        // 64-lane butterfly reduction of both dots
        #pragma unroll
        for (int off = 32; off; off >>= 1) {
            pos += __shfl_xor(pos, off);
            neg += __shfl_xor(neg, off);
        }

        lsum += log_sigmoid(pos) + log_sigmoid(-neg);   // uniform across lanes
    }

    // ---- per-block reduction, one atomic per block ----
    __shared__ float wsum[WAVES_PER_BLOCK];
    if (lane == 0) wsum[wslot] = lsum;
    __syncthreads();
    if (threadIdx.x == 0) {
        float s = 0.0f;
        #pragma unroll
        for (int w = 0; w < WAVES_PER_BLOCK; ++w) s += wsum[w];
        atomicAdd(out, s * neg_inv_b);
    }
}

extern "C" void kernel_launch(void* const* d_in, const int* in_sizes, int n_in,
                              void* d_out, int out_size, void* d_ws, size_t ws_size,
                              hipStream_t stream) {
    const float* u_emb = (const float*)d_in[0];
    const float* v_emb = (const float*)d_in[1];
    const int*   u_pos = (const int*)d_in[2];
    const int*   v_pos = (const int*)d_in[3];
    const int*   v_neg = (const int*)d_in[4];
    float* out = (float*)d_out;

    const int B = in_sizes[2];            // 16384

    hipMemsetAsync(out, 0, sizeof(float), stream);

    const int blocks = 1024;              // 4096 waves, 4 rows each
    skipgram_kernel<<<blocks, WAVES_PER_BLOCK * 64, 0, stream>>>(
        u_emb, v_emb, u_pos, v_pos, v_neg, out, B, -1.0f / (float)B);
}